// Round 11
// baseline (469.285 us; speedup 1.0000x reference)
//
#include <hip/hip_runtime.h>
#include <hip/hip_bf16.h>
#include <hip/hip_cooperative_groups.h>

namespace cg = cooperative_groups;

#define IN_C 128
#define HID 64
#define HEADS 4
#define OUT_C 64
#define NEG_SLOPE 0.2f

typedef __attribute__((ext_vector_type(8))) short bfrag8;   // 8 bf16 (4 VGPR)
typedef __attribute__((ext_vector_type(4))) float facc4;    // mfma C/D

__device__ __forceinline__ float bf16u_to_f(unsigned short u) {
  return __uint_as_float(((unsigned)u) << 16);
}
__device__ __forceinline__ float lof(unsigned u) {           // low bf16 of pair
  return __uint_as_float(u << 16);
}
__device__ __forceinline__ float hif(unsigned u) {           // high bf16 of pair
  return __uint_as_float(u & 0xffff0000u);
}
__device__ __forceinline__ unsigned short f_to_bf16u(float f) {
  return __bfloat16_as_ushort(__float2bfloat16(f));
}
__device__ __forceinline__ float leaky(float x) {
  return (x > 0.f) ? x : NEG_SLOPE * x;
}

// ---------------------------------------------------------------------------
// Setup: W1/W2 -> preswizzled bf16 LDS images (blocks 0..23) + deg zeroing.
// ---------------------------------------------------------------------------
__global__ __launch_bounds__(256) void setup_kernel(
    const float* __restrict__ W1, const float* __restrict__ W2,
    unsigned short* __restrict__ B1img, unsigned short* __restrict__ B2img,
    int* __restrict__ deg, int n) {
  int bid = blockIdx.x;
  if (bid < 24) {
    int i = bid * 256 + threadIdx.x;
    if (i < 4096) {
      int g = i & 7, nn = (i >> 3) & 255, kt = i >> 11;
      unsigned short q[8];
#pragma unroll
      for (int e = 0; e < 8; ++e)
        q[e] = f_to_bf16u(W1[(size_t)(kt * 64 + g * 8 + e) * 256 + nn]);
      *reinterpret_cast<uint4*>(
          &B1img[kt * 16384 + nn * 64 + ((g ^ (nn & 7)) << 3)]) =
          *reinterpret_cast<const uint4*>(q);
    } else if (i < 4096 + 2048) {
      int j = i - 4096;
      int g = j & 7, nn = (j >> 3) & 63, kt = j >> 9;
      unsigned short q[8];
#pragma unroll
      for (int e = 0; e < 8; ++e)
        q[e] = f_to_bf16u(W2[(size_t)(kt * 64 + g * 8 + e) * 64 + nn]);
      *reinterpret_cast<uint4*>(
          &B2img[kt * 4096 + nn * 64 + ((g ^ (nn & 7)) << 3)]) =
          *reinterpret_cast<const uint4*>(q);
    }
  } else {
    int i = (bid - 24) * 1024 + threadIdx.x * 4;
    if (i < n)  // n % 4 == 0
      *reinterpret_cast<int4*>(&deg[i]) = make_int4(0, 0, 0, 0);
  }
}

// ---------------------------------------------------------------------------
// Fused GEMM1 (64x256 tile MFMA + attention epilogue) AND hist_rank.
// ---------------------------------------------------------------------------
__global__ __launch_bounds__(256) void gemm1_hist_kernel(
    const float* __restrict__ A, const unsigned short* __restrict__ B1img,
    const float* __restrict__ att_src, const float* __restrict__ att_dst,
    unsigned short* __restrict__ Hout, float* __restrict__ a_src,
    float* __restrict__ a_dst, int M, int G1,
    const int* __restrict__ dst, int E, int* __restrict__ deg,
    int* __restrict__ rank) {
  __shared__ unsigned short As[64 * 64];    // 8 KB
  __shared__ unsigned short Bs[256 * 64];   // 32 KB
  const int t = threadIdx.x;

  if ((int)blockIdx.x >= G1) {
    int e0 = ((int)blockIdx.x - G1) * 1024 + t * 4;
    if (e0 + 3 < E) {
      int4 d4 = *reinterpret_cast<const int4*>(&dst[e0]);
      int4 r4;
      r4.x = atomicAdd(&deg[d4.x], 1);
      r4.y = atomicAdd(&deg[d4.y], 1);
      r4.z = atomicAdd(&deg[d4.z], 1);
      r4.w = atomicAdd(&deg[d4.w], 1);
      *reinterpret_cast<int4*>(&rank[e0]) = r4;
    } else {
      for (int e = e0; e < E; ++e) rank[e] = atomicAdd(&deg[dst[e]], 1);
    }
    return;
  }

  const int wid = t >> 6, lane = t & 63;
  const int lg = lane >> 4, li = lane & 15;
  const int bm = blockIdx.x * 64;

  facc4 acc[16];
#pragma unroll
  for (int fn = 0; fn < 16; ++fn) acc[fn] = (facc4)(0.f);

#pragma unroll
  for (int kt = 0; kt < 2; ++kt) {
#pragma unroll
    for (int p = 0; p < 2; ++p) {
      int flat = t + p * 256;
      int row = flat >> 3, g = flat & 7;
      int gr = bm + row;
      float4 v0 = make_float4(0.f, 0.f, 0.f, 0.f), v1 = v0;
      if (gr < M) {
        const float* src = &A[(size_t)gr * 128 + kt * 64 + g * 8];
        v0 = *reinterpret_cast<const float4*>(src);
        v1 = *reinterpret_cast<const float4*>(src + 4);
      }
      unsigned short q[8];
      q[0] = f_to_bf16u(v0.x); q[1] = f_to_bf16u(v0.y);
      q[2] = f_to_bf16u(v0.z); q[3] = f_to_bf16u(v0.w);
      q[4] = f_to_bf16u(v1.x); q[5] = f_to_bf16u(v1.y);
      q[6] = f_to_bf16u(v1.z); q[7] = f_to_bf16u(v1.w);
      *reinterpret_cast<uint4*>(&As[row * 64 + ((g ^ (row & 7)) << 3)]) =
          *reinterpret_cast<const uint4*>(q);
    }
#pragma unroll
    for (int p = 0; p < 8; ++p) {
      int gi = t + p * 256;
      *reinterpret_cast<uint4*>(&Bs[gi * 8]) =
          *reinterpret_cast<const uint4*>(&B1img[kt * 16384 + gi * 8]);
    }
    __syncthreads();
#pragma unroll
    for (int ks = 0; ks < 2; ++ks) {
      int arow = wid * 16 + li;
      int gk = ks * 4 + lg;
      bfrag8 a = *reinterpret_cast<const bfrag8*>(
          &As[arow * 64 + ((gk ^ (arow & 7)) << 3)]);
#pragma unroll
      for (int fn = 0; fn < 16; ++fn) {
        int col = fn * 16 + li;
        bfrag8 b = *reinterpret_cast<const bfrag8*>(
            &Bs[col * 64 + ((gk ^ (col & 7)) << 3)]);
        acc[fn] =
            __builtin_amdgcn_mfma_f32_16x16x32_bf16(a, b, acc[fn], 0, 0, 0);
      }
    }
    __syncthreads();
  }

#pragma unroll
  for (int reg = 0; reg < 4; ++reg) {
    int row = bm + wid * 16 + lg * 4 + reg;
    if (row < M) {
#pragma unroll
      for (int fn = 0; fn < 16; ++fn)
        Hout[(size_t)row * 256 + fn * 16 + li] = f_to_bf16u(acc[fn][reg]);
    }
#pragma unroll
    for (int h = 0; h < 4; ++h) {
      float ps = 0.f, pd = 0.f;
#pragma unroll
      for (int q = 0; q < 4; ++q) {
        int fn = h * 4 + q;
        float c = acc[fn][reg];
        ps += c * att_src[fn * 16 + li];
        pd += c * att_dst[fn * 16 + li];
      }
#pragma unroll
      for (int m = 1; m < 16; m <<= 1) {
        ps += __shfl_xor(ps, m);
        pd += __shfl_xor(pd, m);
      }
      if (row < M && li == 0) {
        a_src[(size_t)row * 4 + h] = ps;
        a_dst[(size_t)row * 4 + h] = pd;
      }
    }
  }
}

// ---------------------------------------------------------------------------
// GEMM2: 64x64 tile, K=256, bf16 A (hact), preswizzled B image.
// ---------------------------------------------------------------------------
__global__ __launch_bounds__(256) void mfma_gemm2(
    const unsigned short* __restrict__ A, const unsigned short* __restrict__ B2img,
    const float* __restrict__ att_src, const float* __restrict__ att_dst,
    unsigned short* __restrict__ Hout, float* __restrict__ a_src,
    float* __restrict__ a_dst, int M) {
  __shared__ unsigned short As[64 * 64];
  __shared__ unsigned short Bs[64 * 64];
  const int t = threadIdx.x;
  const int wid = t >> 6, lane = t & 63;
  const int lg = lane >> 4, li = lane & 15;
  const int bm = blockIdx.x * 64;

  facc4 acc[4];
#pragma unroll
  for (int fn = 0; fn < 4; ++fn) acc[fn] = (facc4)(0.f);

#pragma unroll
  for (int kt = 0; kt < 4; ++kt) {
#pragma unroll
    for (int p = 0; p < 2; ++p) {
      int flat = t + p * 256;
      int row = flat >> 3, g = flat & 7;
      int gr = bm + row;
      uint4 v = make_uint4(0, 0, 0, 0);
      if (gr < M)
        v = *reinterpret_cast<const uint4*>(&A[(size_t)gr * 256 + kt * 64 + g * 8]);
      *reinterpret_cast<uint4*>(&As[row * 64 + ((g ^ (row & 7)) << 3)]) = v;
    }
#pragma unroll
    for (int p = 0; p < 2; ++p) {
      int gi = t + p * 256;
      *reinterpret_cast<uint4*>(&Bs[gi * 8]) =
          *reinterpret_cast<const uint4*>(&B2img[kt * 4096 + gi * 8]);
    }
    __syncthreads();
#pragma unroll
    for (int ks = 0; ks < 2; ++ks) {
      int arow = wid * 16 + li;
      int gk = ks * 4 + lg;
      bfrag8 a = *reinterpret_cast<const bfrag8*>(
          &As[arow * 64 + ((gk ^ (arow & 7)) << 3)]);
#pragma unroll
      for (int fn = 0; fn < 4; ++fn) {
        int col = fn * 16 + li;
        bfrag8 b = *reinterpret_cast<const bfrag8*>(
            &Bs[col * 64 + ((gk ^ (col & 7)) << 3)]);
        acc[fn] =
            __builtin_amdgcn_mfma_f32_16x16x32_bf16(a, b, acc[fn], 0, 0, 0);
      }
    }
    __syncthreads();
  }

  float s_att[4], d_att[4];
#pragma unroll
  for (int fn = 0; fn < 4; ++fn) {
    s_att[fn] = att_src[fn * 16 + li];
    d_att[fn] = att_dst[fn * 16 + li];
  }
#pragma unroll
  for (int reg = 0; reg < 4; ++reg) {
    int row = bm + wid * 16 + lg * 4 + reg;
    float ps = 0.f, pd = 0.f;
#pragma unroll
    for (int fn = 0; fn < 4; ++fn) {
      float c = acc[fn][reg];
      ps += c * s_att[fn];
      pd += c * d_att[fn];
    }
#pragma unroll
    for (int m = 1; m < 16; m <<= 1) {
      ps += __shfl_xor(ps, m);
      pd += __shfl_xor(pd, m);
    }
    if (row < M) {
#pragma unroll
      for (int fn = 0; fn < 4; ++fn)
        Hout[(size_t)row * 64 + fn * 16 + li] = f_to_bf16u(acc[fn][reg]);
      if (li == 0) {
        a_src[row] = ps;
        a_dst[row] = pd;
      }
    }
  }
}

// ---------------------------------------------------------------------------
// Cooperative CSR kernel: scan-partial -> grid.sync -> scan-expand ->
// grid.sync -> grid-stride atomic-free scatter. One dispatch.
// ---------------------------------------------------------------------------
__device__ __forceinline__ int pad4(int d) { return (d + 3) & ~3; }

__global__ __launch_bounds__(256) void csr_coop_kernel(
    const int* __restrict__ deg, int n, int nb, int* __restrict__ partials,
    int* __restrict__ offsets, int* __restrict__ ssrc,
    const int* __restrict__ src, const int* __restrict__ dst,
    const int* __restrict__ rank, int E) {
  cg::grid_group grid = cg::this_grid();
  __shared__ int sm[256];
  __shared__ int smp[256];
  int t = threadIdx.x;
  int b = blockIdx.x;

  // Phase A: per-chunk padded-degree sums.
  if (b < nb) {
    int i = b * 256 + t;
    sm[t] = (i < n) ? pad4(deg[i]) : 0;
    __syncthreads();
    for (int off = 128; off > 0; off >>= 1) {
      if (t < off) sm[t] += sm[t + off];
      __syncthreads();
    }
    if (t == 0) partials[b] = sm[0];
  }
  grid.sync();

  // Phase B: expand (local scan of partials + local scan + pad-fill).
  if (b < nb) {
    smp[t] = (t < nb) ? partials[t] : 0;
    __syncthreads();
    for (int off = 1; off < 256; off <<= 1) {
      int u = (t >= off) ? smp[t - off] : 0;
      __syncthreads();
      smp[t] += u;
      __syncthreads();
    }
    int base = (b > 0) ? smp[b - 1] : 0;
    int i = b * 256 + t;
    int d = (i < n) ? deg[i] : 0;
    int v = pad4(d);
    sm[t] = v;
    __syncthreads();
    for (int off = 1; off < 256; off <<= 1) {
      int u = (t >= off) ? sm[t - off] : 0;
      __syncthreads();
      sm[t] += u;
      __syncthreads();
    }
    int excl = sm[t] - v + base;
    if (i < n) {
      offsets[i] = excl;
      for (int k = d; k < v; ++k) ssrc[excl + k] = -1;  // pad slots
    }
  }
  grid.sync();

  // Phase C: scatter, grid-stride, 4 edges/thread.
  int stride4 = gridDim.x * 256 * 4;
  for (int e0 = (b * 256 + t) * 4; e0 < E; e0 += stride4) {
    if (e0 + 3 < E) {
      int4 s4 = *reinterpret_cast<const int4*>(&src[e0]);
      int4 d4 = *reinterpret_cast<const int4*>(&dst[e0]);
      int4 r4 = *reinterpret_cast<const int4*>(&rank[e0]);
      ssrc[offsets[d4.x] + r4.x] = s4.x;
      ssrc[offsets[d4.y] + r4.y] = s4.y;
      ssrc[offsets[d4.z] + r4.z] = s4.z;
      ssrc[offsets[d4.w] + r4.w] = s4.w;
    } else {
      for (int e = e0; e < E; ++e) ssrc[offsets[dst[e]] + rank[e]] = src[e];
    }
  }
}

// ---------------------------------------------------------------------------
// Layer-1 aggregation: 2-phase unrolled gather pipeline (zero queue movs),
// lane-cooperative p. Lane l -> ch 4l..4l+3, head = l>>4. (R9-verified.)
// ---------------------------------------------------------------------------
__global__ __launch_bounds__(256) void agg1_kernel(
    const unsigned short* __restrict__ h1, const float* __restrict__ as1,
    const float* __restrict__ ad1, const int* __restrict__ ssrc,
    const int* __restrict__ offsets, const int* __restrict__ deg,
    const float* __restrict__ bias, unsigned short* __restrict__ out,
    int n_nodes) {
  int wave = (int)((blockIdx.x * blockDim.x + threadIdx.x) >> 6);
  int lane = threadIdx.x & 63;
  if (wave >= n_nodes) return;
  int head = lane >> 4;
  int off = offsets[wave];
  int cnt = deg[wave];  // >= 1 (self-loop)
  int last = ((cnt + 3) >> 2) - 1;
  const int* S_ = ssrc + off;
  float ad = ad1[wave * 4 + head];
  const int pbase = lane & 48;

  auto ldS = [&](int g) {
    return *reinterpret_cast<const int4*>(S_ + min(g, last) * 4);
  };
  auto gK = [&](int4 S, float* a_out) {
    int sk = (lane & 1) ? S.y : S.x;
    int sk2 = (lane & 1) ? S.w : S.z;
    sk = (lane & 2) ? sk2 : sk;
    *a_out = as1[max(sk, 0) * 4 + head];
    return sk;
  };
  auto mkP = [&](int sk, float a) {
    float pk = (sk >= 0) ? __expf(leaky(a + ad)) : 0.f;
    return make_float4(__shfl(pk, pbase), __shfl(pk, pbase + 1),
                       __shfl(pk, pbase + 2), __shfl(pk, pbase + 3));
  };
  auto gat = [&](int s) {
    return *reinterpret_cast<const uint2*>(
        &h1[(size_t)max(s, 0) * 256 + lane * 4]);
  };

  float l = 0.f, a0 = 0.f, a1 = 0.f, a2 = 0.f, a3 = 0.f;

  int4 Sg0 = ldS(0), Sg1 = ldS(1);
  int4 SgP = ldS(2);
  uint2 HA0 = gat(Sg0.x), HA1 = gat(Sg0.y), HA2 = gat(Sg0.z), HA3 = gat(Sg0.w);
  uint2 HB0 = gat(Sg1.x), HB1 = gat(Sg1.y), HB2 = gat(Sg1.z), HB3 = gat(Sg1.w);
  float aKA, aKB;
  int skA = gK(Sg0, &aKA);
  int skB = gK(Sg1, &aKB);
  float4 PA = mkP(skA, aKA), PB;

  int j = 0;
  auto step = [&](float4& Pc, float4& Pn, uint2& Hc0, uint2& Hc1, uint2& Hc2,
                  uint2& Hc3, int& skN, float& aKN, int skC, float aKC) {
    Pn = mkP(skC, aKC);
    skN = gK(SgP, &aKN);
    l += Pc.x + Pc.y + Pc.z + Pc.w;
    a0 += Pc.x * lof(Hc0.x) + Pc.y * lof(Hc1.x) + Pc.z * lof(Hc2.x) +
          Pc.w * lof(Hc3.x);
    a1 += Pc.x * hif(Hc0.x) + Pc.y * hif(Hc1.x) + Pc.z * hif(Hc2.x) +
          Pc.w * hif(Hc3.x);
    a2 += Pc.x * lof(Hc0.y) + Pc.y * lof(Hc1.y) + Pc.z * lof(Hc2.y) +
          Pc.w * lof(Hc3.y);
    a3 += Pc.x * hif(Hc0.y) + Pc.y * hif(Hc1.y) + Pc.z * hif(Hc2.y) +
          Pc.w * hif(Hc3.y);
    Hc0 = gat(SgP.x); Hc1 = gat(SgP.y); Hc2 = gat(SgP.z); Hc3 = gat(SgP.w);
    SgP = ldS(j + 3);
  };

  for (;;) {
    step(PA, PB, HA0, HA1, HA2, HA3, skA, aKA, skB, aKB);
    if (++j > last) break;
    step(PB, PA, HB0, HB1, HB2, HB3, skB, aKB, skA, aKA);
    if (++j > last) break;
  }

  float inv = 1.0f / l;
  int col = lane * 4;
  float4 b4 = *reinterpret_cast<const float4*>(&bias[col]);
  float o0 = a0 * inv + b4.x;
  float o1 = a1 * inv + b4.y;
  float o2 = a2 * inv + b4.z;
  float o3 = a3 * inv + b4.w;
  o0 = o0 > 0.f ? o0 : __expf(o0) - 1.f;
  o1 = o1 > 0.f ? o1 : __expf(o1) - 1.f;
  o2 = o2 > 0.f ? o2 : __expf(o2) - 1.f;
  o3 = o3 > 0.f ? o3 : __expf(o3) - 1.f;
  unsigned short q[4];
  q[0] = f_to_bf16u(o0); q[1] = f_to_bf16u(o1);
  q[2] = f_to_bf16u(o2); q[3] = f_to_bf16u(o3);
  *reinterpret_cast<ushort4*>(&out[(size_t)wave * 256 + col]) =
      *reinterpret_cast<const ushort4*>(q);
}

// ---------------------------------------------------------------------------
// Layer-2 aggregation REWORK: one wave per node; per 4-edge group, lane
// quarter (lane>>4) serves edge k; lane loads 8B = 4 channels at (lane&15)*4.
// Partial sums per quarter, cross-quarter shfl_xor reduction at the end.
// 4x fewer gather instructions than 2B/lane.
// ---------------------------------------------------------------------------
__global__ __launch_bounds__(256) void agg2_kernel(
    const unsigned short* __restrict__ h2, const float* __restrict__ as2,
    const float* __restrict__ ad2, const int* __restrict__ ssrc,
    const int* __restrict__ offsets, const int* __restrict__ deg,
    const float* __restrict__ bias, float* __restrict__ out, int n_nodes) {
  int wave = (int)((blockIdx.x * blockDim.x + threadIdx.x) >> 6);
  int lane = threadIdx.x & 63;
  if (wave >= n_nodes) return;
  int off = offsets[wave];
  int cnt = deg[wave];
  int last = ((cnt + 3) >> 2) - 1;
  const int* S_ = ssrc + off;
  float ad = ad2[wave];
  const int eq = lane >> 4;         // edge slot within group
  const int ch4 = (lane & 15) * 4;  // channel base (4 ch = 8B)

  auto ldS = [&](int g) { return S_[min(g, last) * 4 + eq]; };
  auto gat = [&](int s) {
    return *reinterpret_cast<const uint2*>(&h2[(size_t)max(s, 0) * 64 + ch4]);
  };

  float lsum = 0.f, c0 = 0.f, c1 = 0.f, c2 = 0.f, c3 = 0.f;

  int sA = ldS(0);
  uint2 HA = gat(sA);
  float aA = as2[max(sA, 0)];
  int sB = ldS(1);
  uint2 HB = gat(sB);
  float aB = as2[max(sB, 0)];

  int j = 0;
  auto step = [&](int& sC, uint2& HC, float& aC) {
    float e = aC + ad;
    e = (e > 0.f) ? e : NEG_SLOPE * e;
    float p = (sC >= 0) ? __expf(e) : 0.f;
    lsum += p;
    c0 += p * lof(HC.x);
    c1 += p * hif(HC.x);
    c2 += p * lof(HC.y);
    c3 += p * hif(HC.y);
    int sN = ldS(j + 2);
    sC = sN;
    HC = gat(sN);
    aC = as2[max(sN, 0)];
  };

  for (;;) {
    step(sA, HA, aA);
    if (++j > last) break;
    step(sB, HB, aB);
    if (++j > last) break;
  }

  // Reduce across the 4 lane quarters (same channels live at lane^16, lane^32).
  lsum += __shfl_xor(lsum, 16); lsum += __shfl_xor(lsum, 32);
  c0 += __shfl_xor(c0, 16); c0 += __shfl_xor(c0, 32);
  c1 += __shfl_xor(c1, 16); c1 += __shfl_xor(c1, 32);
  c2 += __shfl_xor(c2, 16); c2 += __shfl_xor(c2, 32);
  c3 += __shfl_xor(c3, 16); c3 += __shfl_xor(c3, 32);

  if (lane < 16) {
    float inv = 1.0f / lsum;
    float4 b4 = *reinterpret_cast<const float4*>(&bias[ch4]);
    float4 o = make_float4(c0 * inv + b4.x, c1 * inv + b4.y, c2 * inv + b4.z,
                           c3 * inv + b4.w);
    *reinterpret_cast<float4*>(&out[(size_t)wave * 64 + ch4]) = o;
  }
}

// ---------------------------------------------------------------------------
extern "C" void kernel_launch(void* const* d_in, const int* in_sizes, int n_in,
                              void* d_out, int out_size, void* d_ws,
                              size_t ws_size, hipStream_t stream) {
  const float* x = (const float*)d_in[0];
  const int* edge_index = (const int*)d_in[1];
  const float* W1 = (const float*)d_in[2];
  const float* att_src1 = (const float*)d_in[3];
  const float* att_dst1 = (const float*)d_in[4];
  const float* b1 = (const float*)d_in[5];
  const float* W2 = (const float*)d_in[6];
  const float* att_src2 = (const float*)d_in[7];
  const float* att_dst2 = (const float*)d_in[8];
  const float* b2 = (const float*)d_in[9];

  const int n = in_sizes[0] / IN_C;  // 50000
  const int E = in_sizes[1] / 2;     // 850000
  const int* src = edge_index;
  const int* dst = edge_index + E;
  const int nb = (n + 255) / 256;
  const int stride = (E + 4 * n + 3) & ~3;

  char* ws = (char*)d_ws;
  size_t off = 0;
  auto carve = [&](size_t bytes) -> void* {
    void* p = ws + off;
    off = (off + bytes + 255) & ~(size_t)255;
    return p;
  };
  unsigned short* h1b = (unsigned short*)carve((size_t)n * 256 * 2);
  unsigned short* hact = (unsigned short*)carve((size_t)n * 256 * 2);
  unsigned short* h2b = (unsigned short*)carve((size_t)n * 64 * 2);
  unsigned short* B1img = (unsigned short*)carve(32768 * 2);
  unsigned short* B2img = (unsigned short*)carve(16384 * 2);
  float* as1 = (float*)carve((size_t)n * 4 * 4);
  float* ad1 = (float*)carve((size_t)n * 4 * 4);
  float* as2 = (float*)carve((size_t)n * 4);
  float* ad2 = (float*)carve((size_t)n * 4);
  int* deg = (int*)carve((size_t)n * 4);
  int* offsets = (int*)carve((size_t)n * 4);
  int* rank = (int*)carve((size_t)E * 4);
  int* ssrc = (int*)carve((size_t)stride * 4);
  int* partials = (int*)carve((size_t)nb * 4);

  // Setup: W images + deg zeroing (one dispatch).
  {
    int zb = (n + 1023) / 1024;
    setup_kernel<<<24 + zb, 256, 0, stream>>>(W1, W2, B1img, B2img, deg, n);
  }
  // GEMM1 + attn1 fused, concurrent with hist_rank.
  {
    int G1 = (n + 63) / 64;
    int H = (E + 1023) / 1024;
    gemm1_hist_kernel<<<G1 + H, 256, 0, stream>>>(
        x, B1img, att_src1, att_dst1, h1b, as1, ad1, n, G1, dst, E, deg, rank);
  }
  // CSR scan + scatter in ONE cooperative dispatch.
  {
    int gb = 832;  // >= nb; covers E in one grid-stride pass; co-residency safe
    int n_ = n, nb_ = nb, E_ = E;
    void* args[] = {(void*)&deg,  (void*)&n_,      (void*)&nb_,
                    (void*)&partials, (void*)&offsets, (void*)&ssrc,
                    (void*)&src,  (void*)&dst,     (void*)&rank, (void*)&E_};
    hipLaunchCooperativeKernel((void*)csr_coop_kernel, dim3(gb), dim3(256),
                               args, 0, stream);
  }
  agg1_kernel<<<(n * 64 + 255) / 256, 256, 0, stream>>>(
      h1b, as1, ad1, ssrc, offsets, deg, b1, hact, n);
  mfma_gemm2<<<(n + 63) / 64, 256, 0, stream>>>(hact, B2img, att_src2,
                                                att_dst2, h2b, as2, ad2, n);
  agg2_kernel<<<(n * 64 + 255) / 256, 256, 0, stream>>>(
      h2b, as2, ad2, ssrc, offsets, deg, b2, (float*)d_out, n);
}